// Round 1
// baseline (400.940 us; speedup 1.0000x reference)
//
#include <hip/hip_runtime.h>

#define GSZ    16
#define NVOX   4096        // 16^3
#define BB     4
#define DD     128
#define GD     4           // feature rows per scatter block (LDS = GD*NVOX*4 = 64 KB)
#define NCHUNK 4           // point chunks per (b, d-group)

// ---------------------------------------------------------------------------
// Kernel 1: per-point voxel index (packed ushort, 0xFFFF = masked) + counts
// ---------------------------------------------------------------------------
__global__ void k_voxidx(const float* __restrict__ xyz, const int* __restrict__ mask,
                         unsigned short* __restrict__ idxm, int* __restrict__ counts,
                         int N) {
    int i = blockIdx.x * blockDim.x + threadIdx.x;
    int total = BB * N;
    if (i >= total) return;
    int b = i / N;
    float x = xyz[3 * i + 0];
    float y = xyz[3 * i + 1];
    float z = xyz[3 * i + 2];
    int vx = min(max((int)(x * (float)GSZ), 0), GSZ - 1);
    int vy = min(max((int)(y * (float)GSZ), 0), GSZ - 1);
    int vz = min(max((int)(z * (float)GSZ), 0), GSZ - 1);
    int idx = vz * GSZ * GSZ + vy * GSZ + vx;
    if (mask[i] != 0) {
        idxm[i] = (unsigned short)idx;
        atomicAdd(&counts[b * NVOX + idx], 1);
    } else {
        idxm[i] = 0xFFFFu;  // masked point contributes nothing
    }
}

// ---------------------------------------------------------------------------
// Kernel 2: scatter-add features into LDS voxel accumulators, flush atomically
// block = (b, dg, chunk); 512 threads; 64 KB LDS -> 2 blocks/CU, 16 waves/CU
// ---------------------------------------------------------------------------
__global__ __launch_bounds__(512) void k_scatter(const float* __restrict__ feats,
                                                 const unsigned short* __restrict__ idxm,
                                                 float* __restrict__ out, int N) {
    __shared__ float acc[GD * NVOX];
    int blk = blockIdx.x;
    int c   = blk % NCHUNK;
    int dg  = (blk / NCHUNK) % (DD / GD);
    int b   = blk / (NCHUNK * (DD / GD));

    for (int j = threadIdx.x; j < GD * NVOX; j += blockDim.x) acc[j] = 0.f;
    __syncthreads();

    int chunk = (N + NCHUNK - 1) / NCHUNK;
    int start = c * chunk;
    int end   = min(N, start + chunk);

    const float* f0 = feats + ((size_t)b * DD + (size_t)dg * GD) * (size_t)N;
    const unsigned short* ib = idxm + (size_t)b * N;

    for (int i = start + (int)threadIdx.x; i < end; i += (int)blockDim.x) {
        unsigned int idx = ib[i];
        if (idx != 0xFFFFu) {
#pragma unroll
            for (int k = 0; k < GD; k++) {
                atomicAdd(&acc[k * NVOX + idx], f0[(size_t)k * N + i]);
            }
        }
    }
    __syncthreads();

    float* ob = out + ((size_t)b * DD + (size_t)dg * GD) * (size_t)NVOX;
    for (int j = threadIdx.x; j < GD * NVOX; j += blockDim.x) {
        float v = acc[j];
        if (v != 0.f) atomicAdd(&ob[j], v);
    }
}

// ---------------------------------------------------------------------------
// Kernel 3: divide by max(count,1)
// ---------------------------------------------------------------------------
__global__ void k_divide(float* __restrict__ out, const int* __restrict__ counts) {
    int i = blockIdx.x * blockDim.x + threadIdx.x;
    int total = BB * DD * NVOX;
    if (i >= total) return;
    int v = i & (NVOX - 1);
    int b = i / (DD * NVOX);
    int cnt = counts[b * NVOX + v];
    out[i] = out[i] / (float)max(cnt, 1);
}

extern "C" void kernel_launch(void* const* d_in, const int* in_sizes, int n_in,
                              void* d_out, int out_size, void* d_ws, size_t ws_size,
                              hipStream_t stream) {
    const float* feats = (const float*)d_in[0];          // [B, D, N]
    const float* xyz   = (const float*)d_in[1];          // [B, N, 3]
    const int*   mask  = (const int*)d_in[2];            // [B, N]
    float*       out   = (float*)d_out;                  // [B, D, V]

    int N = in_sizes[2] / BB;                            // mask is B*N

    int*            counts = (int*)d_ws;                                     // B*V ints (64 KB)
    unsigned short* idxm   = (unsigned short*)((char*)d_ws +
                                               (size_t)BB * NVOX * sizeof(int)); // B*N ushorts

    // d_out / d_ws are poisoned before every timed call -> zero what we accumulate into
    hipMemsetAsync(out, 0, (size_t)out_size * sizeof(float), stream);
    hipMemsetAsync(counts, 0, (size_t)BB * NVOX * sizeof(int), stream);

    int total_pts = BB * N;
    k_voxidx<<<(total_pts + 255) / 256, 256, 0, stream>>>(xyz, mask, idxm, counts, N);

    int nblk = BB * (DD / GD) * NCHUNK;                  // 512 blocks
    k_scatter<<<nblk, 512, 0, stream>>>(feats, idxm, out, N);

    int tot_out = BB * DD * NVOX;
    k_divide<<<(tot_out + 255) / 256, 256, 0, stream>>>(out, counts);
}

// Round 2
// 368.022 us; speedup vs baseline: 1.0894x; 1.0894x over previous
//
#include <hip/hip_runtime.h>

#define GSZ    16
#define NVOX   4096        // 16^3
#define BB     4
#define DD     128
#define GD     4           // feature rows per scatter block (LDS = GD*NVOX*4 = 64 KB)
#define NCHUNK 4           // point chunks per (b, d-group)

// ---------------------------------------------------------------------------
// Kernel 1: per-point voxel index (packed ushort, 0xFFFF = masked) + counts
// ---------------------------------------------------------------------------
__global__ void k_voxidx(const float* __restrict__ xyz, const int* __restrict__ mask,
                         unsigned short* __restrict__ idxm, int* __restrict__ counts,
                         int N) {
    int i = blockIdx.x * blockDim.x + threadIdx.x;
    int total = BB * N;
    if (i >= total) return;
    int b = i / N;
    float x = xyz[3 * i + 0];
    float y = xyz[3 * i + 1];
    float z = xyz[3 * i + 2];
    int vx = min(max((int)(x * (float)GSZ), 0), GSZ - 1);
    int vy = min(max((int)(y * (float)GSZ), 0), GSZ - 1);
    int vz = min(max((int)(z * (float)GSZ), 0), GSZ - 1);
    int idx = vz * GSZ * GSZ + vy * GSZ + vx;
    if (mask[i] != 0) {
        idxm[i] = (unsigned short)idx;
        atomicAdd(&counts[b * NVOX + idx], 1);
    } else {
        idxm[i] = 0xFFFFu;  // masked point contributes nothing
    }
}

// ---------------------------------------------------------------------------
// Kernel 2: scatter-add features into LDS voxel accumulators, flush atomically
// block = (b, dg, chunk); 1024 threads; 64 KB LDS -> 2 blocks/CU = 32 waves/CU
// Each thread handles 4 consecutive points: 1 ushort4 + 4 float4 loads/iter.
// ---------------------------------------------------------------------------
__global__ __launch_bounds__(1024, 8) void k_scatter(const float* __restrict__ feats,
                                                     const unsigned short* __restrict__ idxm,
                                                     float* __restrict__ out, int N) {
    __shared__ float acc[GD * NVOX];
    int blk = blockIdx.x;
    int c   = blk % NCHUNK;
    int dg  = (blk / NCHUNK) % (DD / GD);
    int b   = blk / (NCHUNK * (DD / GD));

    float4* accv = (float4*)acc;
    for (int j = threadIdx.x; j < GD * NVOX / 4; j += blockDim.x)
        accv[j] = make_float4(0.f, 0.f, 0.f, 0.f);
    __syncthreads();

    int chunk = (((N + NCHUNK - 1) / NCHUNK) + 3) & ~3;   // multiple of 4
    int start = c * chunk;
    int end   = min(N, start + chunk);

    const float* f0 = feats + ((size_t)b * DD + (size_t)dg * GD) * (size_t)N;
    const unsigned short* ib = idxm + (size_t)b * N;

    for (int i = start + (int)threadIdx.x * 4; i < end; i += (int)blockDim.x * 4) {
        if (i + 3 < end) {
            ushort4 iv = *reinterpret_cast<const ushort4*>(ib + i);
            float4 r0 = *reinterpret_cast<const float4*>(f0 + 0 * (size_t)N + i);
            float4 r1 = *reinterpret_cast<const float4*>(f0 + 1 * (size_t)N + i);
            float4 r2 = *reinterpret_cast<const float4*>(f0 + 2 * (size_t)N + i);
            float4 r3 = *reinterpret_cast<const float4*>(f0 + 3 * (size_t)N + i);
            if (iv.x != 0xFFFFu) {
                atomicAdd(&acc[0 * NVOX + iv.x], r0.x);
                atomicAdd(&acc[1 * NVOX + iv.x], r1.x);
                atomicAdd(&acc[2 * NVOX + iv.x], r2.x);
                atomicAdd(&acc[3 * NVOX + iv.x], r3.x);
            }
            if (iv.y != 0xFFFFu) {
                atomicAdd(&acc[0 * NVOX + iv.y], r0.y);
                atomicAdd(&acc[1 * NVOX + iv.y], r1.y);
                atomicAdd(&acc[2 * NVOX + iv.y], r2.y);
                atomicAdd(&acc[3 * NVOX + iv.y], r3.y);
            }
            if (iv.z != 0xFFFFu) {
                atomicAdd(&acc[0 * NVOX + iv.z], r0.z);
                atomicAdd(&acc[1 * NVOX + iv.z], r1.z);
                atomicAdd(&acc[2 * NVOX + iv.z], r2.z);
                atomicAdd(&acc[3 * NVOX + iv.z], r3.z);
            }
            if (iv.w != 0xFFFFu) {
                atomicAdd(&acc[0 * NVOX + iv.w], r0.w);
                atomicAdd(&acc[1 * NVOX + iv.w], r1.w);
                atomicAdd(&acc[2 * NVOX + iv.w], r2.w);
                atomicAdd(&acc[3 * NVOX + iv.w], r3.w);
            }
        } else {
            for (int p = i; p < end; p++) {
                unsigned int idx = ib[p];
                if (idx != 0xFFFFu) {
#pragma unroll
                    for (int k = 0; k < GD; k++)
                        atomicAdd(&acc[k * NVOX + idx], f0[(size_t)k * N + p]);
                }
            }
        }
    }
    __syncthreads();

    float* ob = out + ((size_t)b * DD + (size_t)dg * GD) * (size_t)NVOX;
    for (int j = threadIdx.x; j < GD * NVOX; j += blockDim.x) {
        float v = acc[j];
        if (v != 0.f) atomicAdd(&ob[j], v);
    }
}

// ---------------------------------------------------------------------------
// Kernel 3: divide by max(count,1), float4-vectorized
// ---------------------------------------------------------------------------
__global__ void k_divide(float* __restrict__ out, const int* __restrict__ counts) {
    int i = blockIdx.x * blockDim.x + threadIdx.x;     // float4 index
    int total4 = BB * DD * NVOX / 4;
    if (i >= total4) return;
    int e0 = i * 4;
    int v  = e0 & (NVOX - 1);                          // NVOX multiple of 4 -> same b, contiguous v
    int b  = e0 / (DD * NVOX);
    const int4 c4 = *reinterpret_cast<const int4*>(&counts[b * NVOX + v]);
    float4 o = reinterpret_cast<float4*>(out)[i];
    o.x /= (float)max(c4.x, 1);
    o.y /= (float)max(c4.y, 1);
    o.z /= (float)max(c4.z, 1);
    o.w /= (float)max(c4.w, 1);
    reinterpret_cast<float4*>(out)[i] = o;
}

extern "C" void kernel_launch(void* const* d_in, const int* in_sizes, int n_in,
                              void* d_out, int out_size, void* d_ws, size_t ws_size,
                              hipStream_t stream) {
    const float* feats = (const float*)d_in[0];          // [B, D, N]
    const float* xyz   = (const float*)d_in[1];          // [B, N, 3]
    const int*   mask  = (const int*)d_in[2];            // [B, N]
    float*       out   = (float*)d_out;                  // [B, D, V]

    int N = in_sizes[2] / BB;                            // mask is B*N

    int*            counts = (int*)d_ws;                                     // B*V ints (64 KB)
    unsigned short* idxm   = (unsigned short*)((char*)d_ws +
                                               (size_t)BB * NVOX * sizeof(int)); // B*N ushorts

    // d_out / d_ws are poisoned before every timed call -> zero what we accumulate into
    hipMemsetAsync(out, 0, (size_t)out_size * sizeof(float), stream);
    hipMemsetAsync(counts, 0, (size_t)BB * NVOX * sizeof(int), stream);

    int total_pts = BB * N;
    k_voxidx<<<(total_pts + 255) / 256, 256, 0, stream>>>(xyz, mask, idxm, counts, N);

    int nblk = BB * (DD / GD) * NCHUNK;                  // 512 blocks, 2 per CU
    k_scatter<<<nblk, 1024, 0, stream>>>(feats, idxm, out, N);

    int tot_out4 = BB * DD * NVOX / 4;
    k_divide<<<(tot_out4 + 255) / 256, 256, 0, stream>>>(out, counts);
}

// Round 3
// 350.429 us; speedup vs baseline: 1.1441x; 1.0502x over previous
//
#include <hip/hip_runtime.h>

#define GSZ  16
#define NVOX 4096        // 16^3
#define BB   4
#define DD   128

// ---------------------------------------------------------------------------
// Kernel 1: per-point voxel index (packed ushort, 0xFFFF = masked) + counts
// grid = ((N+255)/256, B) -- no integer division
// ---------------------------------------------------------------------------
__global__ void k_voxidx(const float* __restrict__ xyz, const int* __restrict__ mask,
                         unsigned short* __restrict__ idxm, int* __restrict__ counts,
                         int N) {
    int n = blockIdx.x * blockDim.x + threadIdx.x;
    int b = blockIdx.y;
    if (n >= N) return;
    size_t i = (size_t)b * N + n;
    float x = xyz[3 * i + 0];
    float y = xyz[3 * i + 1];
    float z = xyz[3 * i + 2];
    int vx = min(max((int)(x * (float)GSZ), 0), GSZ - 1);
    int vy = min(max((int)(y * (float)GSZ), 0), GSZ - 1);
    int vz = min(max((int)(z * (float)GSZ), 0), GSZ - 1);
    int idx = vz * GSZ * GSZ + vy * GSZ + vx;
    if (mask[i] != 0) {
        idxm[i] = (unsigned short)idx;
        atomicAdd(&counts[b * NVOX + idx], 1);
    } else {
        idxm[i] = 0xFFFFu;  // masked point contributes nothing
    }
}

// ---------------------------------------------------------------------------
// Kernel 2: each block owns one (b, d) output row. 1024 threads, 16 KB LDS
// (2 blocks/CU = 32 waves/CU). Points scattered into LDS via ds_add_f32;
// flush = plain coalesced stores with the count-divide fused (no global
// atomics, no out-memset, no separate divide kernel).
// 8 points/thread/iter, software-pipelined (next loads issued before current
// LDS atomics).
// ---------------------------------------------------------------------------
__global__ __launch_bounds__(1024, 8) void k_scatter(const float* __restrict__ feats,
                                                     const unsigned short* __restrict__ idxm,
                                                     const int* __restrict__ counts,
                                                     float* __restrict__ out, int N) {
    __shared__ float acc[NVOX];
    int d = blockIdx.x & (DD - 1);
    int b = blockIdx.x >> 7;   // DD == 128

    for (int j = threadIdx.x; j < NVOX; j += 1024) acc[j] = 0.f;
    __syncthreads();

    const float*          f  = feats + ((size_t)b * DD + (size_t)d) * (size_t)N;
    const unsigned short* ib = idxm + (size_t)b * N;

    const int stride = 1024 * 8;
    const int nmain  = (N / stride) * stride;       // multiple-of-8192 region
    const int niter  = nmain / stride;
    const int t8     = (int)threadIdx.x * 8;

#define PROC(id, val)                                        \
    {                                                        \
        unsigned int _i = (id);                              \
        if (_i != 0xFFFFu) atomicAdd(&acc[_i], (val));       \
    }

    if (niter > 0) {
        uint4  iv = *reinterpret_cast<const uint4*>(ib + t8);     // 8 ushort idx
        float4 r0 = *reinterpret_cast<const float4*>(f + t8);
        float4 r1 = *reinterpret_cast<const float4*>(f + t8 + 4);
        for (int it = 0; it < niter; it++) {
            int inext = (it + 1 < niter) ? (it + 1) * stride + t8 : t8;  // dummy for last
            uint4  ivn = *reinterpret_cast<const uint4*>(ib + inext);
            float4 r0n = *reinterpret_cast<const float4*>(f + inext);
            float4 r1n = *reinterpret_cast<const float4*>(f + inext + 4);

            PROC(iv.x & 0xFFFFu, r0.x)
            PROC(iv.x >> 16,     r0.y)
            PROC(iv.y & 0xFFFFu, r0.z)
            PROC(iv.y >> 16,     r0.w)
            PROC(iv.z & 0xFFFFu, r1.x)
            PROC(iv.z >> 16,     r1.y)
            PROC(iv.w & 0xFFFFu, r1.z)
            PROC(iv.w >> 16,     r1.w)

            iv = ivn; r0 = r0n; r1 = r1n;
        }
    }
    // tail: points [nmain, N)
    for (int p = nmain + (int)threadIdx.x; p < N; p += 1024) {
        unsigned int id = ib[p];
        if (id != 0xFFFFu) atomicAdd(&acc[id], f[p]);
    }
#undef PROC

    __syncthreads();

    // flush with fused divide: out[b, d, :] = acc[:] / max(count, 1)
    const int* cb = counts + b * NVOX;
    float*     ob = out + ((size_t)b * DD + (size_t)d) * (size_t)NVOX;
    {
        int j = threadIdx.x;                       // NVOX/4 == 1024 == blockDim
        float4 a = reinterpret_cast<float4*>(acc)[j];
        int4   c = reinterpret_cast<const int4*>(cb)[j];
        a.x /= (float)max(c.x, 1);
        a.y /= (float)max(c.y, 1);
        a.z /= (float)max(c.z, 1);
        a.w /= (float)max(c.w, 1);
        reinterpret_cast<float4*>(ob)[j] = a;
    }
}

extern "C" void kernel_launch(void* const* d_in, const int* in_sizes, int n_in,
                              void* d_out, int out_size, void* d_ws, size_t ws_size,
                              hipStream_t stream) {
    const float* feats = (const float*)d_in[0];          // [B, D, N]
    const float* xyz   = (const float*)d_in[1];          // [B, N, 3]
    const int*   mask  = (const int*)d_in[2];            // [B, N]
    float*       out   = (float*)d_out;                  // [B, D, V]

    int N = in_sizes[2] / BB;                            // mask is B*N

    int*            counts = (int*)d_ws;                                     // B*V ints (64 KB)
    unsigned short* idxm   = (unsigned short*)((char*)d_ws +
                                               (size_t)BB * NVOX * sizeof(int)); // B*N ushorts

    // counts is accumulated -> must start at zero (ws is poisoned each call)
    hipMemsetAsync(counts, 0, (size_t)BB * NVOX * sizeof(int), stream);

    k_voxidx<<<dim3((N + 255) / 256, BB), 256, 0, stream>>>(xyz, mask, idxm, counts, N);

    // 512 blocks = B*D, each owns one output row; out fully written by stores
    k_scatter<<<BB * DD, 1024, 0, stream>>>(feats, idxm, counts, out, N);
}